// Round 6
// baseline (375.616 us; speedup 1.0000x reference)
//
#include <hip/hip_runtime.h>

// Per-voxel LUT gather + scale + onehot, all float32.
//   out[i]     = paren[i] * scale(lab[i]), scale(0) == 1.0  (bg bit-exact)
//   onehot ch0 = lab==0, ch1 = dark vessel, ch2 = bright vessel
//
// R11: slab-grained channel phasing with L3-resident labels.
// Evidence chain: R8 (3x diagnostic) kernel = 4.1 TB/s, single-pass ~88 us
// = 4.6 TB/s on the 6-stream 1R:2W mix; fill = 6.6 (1 write stream); copy
// = 6.3 (1R:1W). R10 (full-volume channel phases) improved the DRAM rate to
// ~5.3 TB/s but paid 3x extra HBM label reads (re-read distance ~192+ MB
// evicted labels from the 256 MB memory-side Infinity Cache) -> net +21 us.
// R11 keeps the phase separation but shrinks the re-read distance: 2 slabs
// x 4 channel-phases x 1024 blocks. Per slab only ~96 MB streams between a
// labels chunk's first read (phase c0) and its re-reads (c1..c3) -> MALL
// serves them, HBM traffic stays at the mandatory 384 MiB. 512-thread
// blocks: 4 blocks/CU -> ~1024 blocks in flight = exactly one phase, so
// phases separate in time (1-2 live DRAM streams chip-wide).
// NT loads + NT stores (R9: plain stores -8 us). R7 1 KB wave-burst
// addressing kept (R6->R7 burst-doubling null => 4 KB/stream sufficient).

constexpr unsigned int VOX = 256u * 256u * 256u;  // 16,777,216
constexpr int N_IDS = 256;

typedef int   vint4  __attribute__((ext_vector_type(4)));
typedef float vflt4  __attribute__((ext_vector_type(4)));

__global__ __launch_bounds__(512)
void synth_semantic_kernel(const int* __restrict__ labels,
                           const float* __restrict__ id_intensity,
                           const int* __restrict__ id_is_dark,
                           const float* __restrict__ paren,
                           float* __restrict__ out)
{
    // LUT: bits[30:0] = f32 scale (id 0 forced to 1.0; scale in (0,2) so the
    // sign bit is free), bit 31 = dark flag.
    __shared__ unsigned int lut[N_IDS];
    const int t = threadIdx.x;
    if (t < N_IDS) {
        float sc = (t == 0) ? 1.0f : id_intensity[t];
        union { float f; unsigned int u; } cv; cv.f = sc;
        lut[t] = (cv.u & 0x7FFFFFFFu) | ((id_is_dark[t] == 1) ? 0x80000000u : 0u);
    }
    __syncthreads();

    // Grid: bid = slab(1b) | channel-phase(2b) | chunk(10b), phase-major
    // within slab so all chunk-blocks of one channel dispatch together.
    const unsigned int slab  = blockIdx.x >> 12;          // 0..1
    const unsigned int within = blockIdx.x & 4095u;
    const unsigned int seg   = within >> 10;              // channel phase 0..3
    const unsigned int chunk = within & 1023u;            // 0..1023
    // Block covers 8192 voxels: 8 waves x 1024.
    const unsigned int lane  = (unsigned int)t & 63u;
    const unsigned int base  = slab * (VOX / 2u) + chunk * 8192u
                             + ((unsigned int)t >> 6) * 1024u + lane * 4u;

    // Labels: 4 x 1 KB wave-contiguous NT loads (16 voxels/thread).
    vint4 l[4];
#pragma unroll
    for (int g = 0; g < 4; ++g)
        l[g] = __builtin_nontemporal_load((const vint4*)(labels + base + 256u * g));

    if (seg == 0) {
        // out = paren * scale(lab); bg keeps *1.0f (bit-exact).
        vflt4 p[4];
#pragma unroll
        for (int g = 0; g < 4; ++g)
            p[g] = __builtin_nontemporal_load((const vflt4*)(paren + base + 256u * g));
#pragma unroll
        for (int g = 0; g < 4; ++g) {
            const int   labs[4] = {l[g].x, l[g].y, l[g].z, l[g].w};
            const float pv[4]   = {p[g].x, p[g].y, p[g].z, p[g].w};
            float oo[4];
#pragma unroll
            for (int j = 0; j < 4; ++j) {
                union { unsigned int u; float f; } sc;
                sc.u = lut[labs[j]] & 0x7FFFFFFFu;
                oo[j] = pv[j] * sc.f;
            }
            const vflt4 v = (vflt4){oo[0], oo[1], oo[2], oo[3]};
            __builtin_nontemporal_store(v, (vflt4*)(out + base + 256u * g));
        }
    } else {
        // One onehot channel from labels alone (labels chunk expected
        // MALL-resident from this slab's seg-0 pass).
#pragma unroll
        for (int g = 0; g < 4; ++g) {
            const int labs[4] = {l[g].x, l[g].y, l[g].z, l[g].w};
            float oo[4];
#pragma unroll
            for (int j = 0; j < 4; ++j) {
                const int lab = labs[j];
                const unsigned int darkbit = lut[lab] >> 31;
                bool f;
                if (seg == 1)      f = (lab == 0);
                else if (seg == 2) f = (lab != 0) && darkbit;
                else               f = (lab != 0) && !darkbit;
                oo[j] = f ? 1.0f : 0.0f;
            }
            const vflt4 v = (vflt4){oo[0], oo[1], oo[2], oo[3]};
            __builtin_nontemporal_store(v, (vflt4*)(out + seg * VOX + base + 256u * g));
        }
    }
}

extern "C" void kernel_launch(void* const* d_in, const int* in_sizes, int n_in,
                              void* d_out, int out_size, void* d_ws, size_t ws_size,
                              hipStream_t stream) {
    const int*   labels  = (const int*)d_in[0];
    const float* id_int  = (const float*)d_in[1];
    const int*   id_dark = (const int*)d_in[2];
    const float* paren   = (const float*)d_in[3];
    float*       outp    = (float*)d_out;

    // 2 slabs x 4 channel-phases x 1024 chunk-blocks, 512 threads/block.
    const unsigned int blocks = 8192u;
    synth_semantic_kernel<<<dim3(blocks), dim3(512), 0, stream>>>(
        labels, id_int, id_dark, paren, outp);
}

// Round 7
// 353.309 us; speedup vs baseline: 1.0631x; 1.0631x over previous
//
#include <hip/hip_runtime.h>

// Per-voxel LUT gather + scale + onehot, all float32.
//   out[i]     = paren[i] * scale(lab[i]), scale(0) == 1.0  (bg bit-exact)
//   onehot ch0 = lab==0, ch1 = dark vessel, ch2 = bright vessel
// Traffic: 8 B read + 16 B write per voxel -> 403 MB mandatory.
//
// R12 = R7 restored (best measured: 354.06 us total; kernel ~88 us).
// Experiment ledger on the kernel's ~24 us of theoretical headroom
// (88 us @ 4.6 TB/s vs ~64 us @ 6.3 TB/s):
//   R6->R7  burst 2->4 KB/stream, half the instructions   -> null
//   R8      3x diagnostic: kernel row = 4.1 TB/s visible  -> regime = 1R:2W
//           6-stream mix; fill=6.6 (1W), copy=6.3 (1R:1W)
//   R9      plain stores (L2 aggregation theory)          -> +8 us (L2 thrash;
//           NT direct-to-HBM is right for 256 MB streamed writes)
//   R10     channel-phased grid (1-2 streams per phase)   -> +21 us (3x label
//           re-reads from HBM outweigh better DRAM rate)
//   R11     slab-phased (re-reads inside 256 MB MALL)     -> +21 us (no change
//           vs R10: dispatch doesn't phase-separate)
// Conclusion: the 6-stream R/W mix rate (~4.6 TB/s) is the structural limit
// for this problem shape on this chip; every kernel-side topology lever is
// null or negative. This kernel is the roofline configuration.

constexpr unsigned int VOX = 256u * 256u * 256u;  // 16,777,216
constexpr int N_IDS = 256;

typedef int   vint4  __attribute__((ext_vector_type(4)));
typedef float vflt4  __attribute__((ext_vector_type(4)));

__global__ __launch_bounds__(256)
void synth_semantic_kernel(const int* __restrict__ labels,
                           const float* __restrict__ id_intensity,
                           const int* __restrict__ id_is_dark,
                           const float* __restrict__ paren,
                           float* __restrict__ out)
{
    // LUT: bits[30:0] = f32 scale (id 0 forced to 1.0; scale in (0,2) so the
    // sign bit is free), bit 31 = dark flag. One ds_read_b32 per voxel.
    __shared__ unsigned int lut[N_IDS];
    const int t = threadIdx.x;
    {
        float sc = (t == 0) ? 1.0f : id_intensity[t];
        union { float f; unsigned int u; } cv; cv.f = sc;
        lut[t] = (cv.u & 0x7FFFFFFFu) | ((id_is_dark[t] == 1) ? 0x80000000u : 0u);
    }
    __syncthreads();

    // Wave w owns voxels [w*1024, w*1024+1024); lane l handles four float4
    // groups at w*1024 + 4l + {0,256,512,768}. Every ld/st instruction is a
    // contiguous aligned 1 KB per wave; per stream the wave touches 4 KB.
    const unsigned int lane = (unsigned int)t & 63u;
    const unsigned int wave = (blockIdx.x * 256u + (unsigned int)t) >> 6;
    const unsigned int base = wave * 1024u + lane * 4u;

    // Issue all 8 loads up front (8 KB/wave in flight). NT: never reused.
    vint4 l[4]; vflt4 p[4];
#pragma unroll
    for (int g = 0; g < 4; ++g) {
        l[g] = __builtin_nontemporal_load((const vint4*)(labels + base + 256u * g));
        p[g] = __builtin_nontemporal_load((const vflt4*)(paren  + base + 256u * g));
    }

    vflt4 o[4], bg[4], dk[4], br[4];
#pragma unroll
    for (int g = 0; g < 4; ++g) {
        const int   labs[4] = {l[g].x, l[g].y, l[g].z, l[g].w};
        const float pv[4]   = {p[g].x, p[g].y, p[g].z, p[g].w};
        float oo[4], ob[4], od[4], orr[4];
#pragma unroll
        for (int j = 0; j < 4; ++j) {
            const int lab = labs[j];
            const unsigned int e = lut[lab];
            union { unsigned int u; float f; } sc; sc.u = e & 0x7FFFFFFFu;
            const bool isbg = (lab == 0);
            const bool isdk = (!isbg) && (e >> 31);
            const bool isbr = (!isbg) && !(e >> 31);
            oo[j]  = pv[j] * sc.f;          // bg: *1.0f, bit-exact
            ob[j]  = isbg ? 1.0f : 0.0f;
            od[j]  = isdk ? 1.0f : 0.0f;
            orr[j] = isbr ? 1.0f : 0.0f;
        }
        o[g]  = (vflt4){oo[0],  oo[1],  oo[2],  oo[3]};
        bg[g] = (vflt4){ob[0],  ob[1],  ob[2],  ob[3]};
        dk[g] = (vflt4){od[0],  od[1],  od[2],  od[3]};
        br[g] = (vflt4){orr[0], orr[1], orr[2], orr[3]};
    }

    // Stream-major NT stores: 4 consecutive 1 KB wave-bursts (4 KB
    // contiguous) per output stream before switching streams.
#pragma unroll
    for (int g = 0; g < 4; ++g)
        __builtin_nontemporal_store(o[g],  (vflt4*)(out + base + 256u * g));
#pragma unroll
    for (int g = 0; g < 4; ++g)
        __builtin_nontemporal_store(bg[g], (vflt4*)(out + VOX + base + 256u * g));
#pragma unroll
    for (int g = 0; g < 4; ++g)
        __builtin_nontemporal_store(dk[g], (vflt4*)(out + 2u * VOX + base + 256u * g));
#pragma unroll
    for (int g = 0; g < 4; ++g)
        __builtin_nontemporal_store(br[g], (vflt4*)(out + 3u * VOX + base + 256u * g));
}

extern "C" void kernel_launch(void* const* d_in, const int* in_sizes, int n_in,
                              void* d_out, int out_size, void* d_ws, size_t ws_size,
                              hipStream_t stream) {
    const int*   labels  = (const int*)d_in[0];
    const float* id_int  = (const float*)d_in[1];
    const int*   id_dark = (const int*)d_in[2];
    const float* paren   = (const float*)d_in[3];
    float*       outp    = (float*)d_out;

    const unsigned int threads_total = VOX / 16u;      // 1,048,576
    const unsigned int blocks = threads_total / 256u;  // 4,096
    synth_semantic_kernel<<<dim3(blocks), dim3(256), 0, stream>>>(
        labels, id_int, id_dark, paren, outp);
}